// Round 9
// baseline (97.204 us; speedup 1.0000x reference)
//
#include <hip/hip_runtime.h>
#include <math.h>

#define B_  32
#define N_  100
#define G_  32
#define D_  1024
#define DG_ 32
#define FD_ 64

typedef __attribute__((ext_vector_type(8))) short short8;
typedef __attribute__((ext_vector_type(8))) unsigned short ushort8;
typedef __attribute__((ext_vector_type(4))) unsigned short ushort4v;
typedef __attribute__((ext_vector_type(4))) float f32x4;

__device__ inline unsigned short f2bf(float f) {
    unsigned int x = __float_as_uint(f);
    unsigned int r = (x + 0x7fffu + ((x >> 16) & 1u)) >> 16;  // RNE
    return (unsigned short)r;
}
__device__ inline unsigned short f2h(float f) {
    _Float16 h = (_Float16)f;
    return __builtin_bit_cast(unsigned short, h);
}
__device__ inline float h2f(unsigned short u) {
    return (float)__builtin_bit_cast(_Float16, u);
}
__device__ inline void load_lds16(const void* g, void* l) {
    __builtin_amdgcn_global_load_lds(
        (const __attribute__((address_space(1))) void*)g,
        (__attribute__((address_space(3))) void*)l, 16, 0, 0);
}

// ---------------------------------------------------------------------------
// Fused prep: [0,256) mask detect (1/8 scan) | [256,272) bbox prep |
// [272,1872) feat cast | [1872,2384) q_w | [2384,2896) k_w | [2896,3408) conv_w.
// ---------------------------------------------------------------------------
__global__ __launch_bounds__(256) void prep_kernel(
    const unsigned int* __restrict__ mask, int* __restrict__ flag,
    const float* __restrict__ bbox, float* __restrict__ prep,
    const float* __restrict__ feat, unsigned short* __restrict__ featb,
    const float* __restrict__ qw, unsigned short* __restrict__ wqb,
    const float* __restrict__ kw, unsigned short* __restrict__ wkb,
    const float* __restrict__ cw, unsigned short* __restrict__ wcb)
{
    const int bid = blockIdx.x;
    const int t = threadIdx.x;
    if (bid < 256) {
        const int nwords = (B_ * N_ * G_ * N_) / 4 / 8;   // 1/8 scan
        int v = 0;
        for (int i = bid * 256 + t; i < nwords; i += 256 * 256)
            v |= (mask[i] > 1u) ? 1 : 0;
        if (__any(v) && (t & 63) == 0) atomicOr(flag, 1);
        return;
    }
    if (bid < 272) {
        const int i = (bid - 256) * 256 + t;
        if (i < B_ * N_) {
            const float4 bb = *reinterpret_cast<const float4*>(bbox + (size_t)i * 4);
            const float bw = bb.z - bb.x + 1.0f, bh = bb.w - bb.y + 1.0f;
            float4 o0, o1;
            o0.x = 0.5f * (bb.x + bb.z);
            o0.y = 0.5f * (bb.y + bb.w);
            o0.z = __logf(bw);
            o0.w = __logf(bh);
            o1.x = 1.0f / bw;
            o1.y = 1.0f / bh;
            o1.z = 0.0f; o1.w = 0.0f;
            *reinterpret_cast<float4*>(prep + (size_t)i * 8)     = o0;
            *reinterpret_cast<float4*>(prep + (size_t)i * 8 + 4) = o1;
        }
        return;
    }
    const float* src;
    unsigned short* dst;
    int i;
    if (bid < 1872)      { src = feat; dst = featb; i = (bid - 272) * 256 + t; }
    else if (bid < 2384) { src = qw;   dst = wqb;   i = (bid - 1872) * 256 + t; }
    else if (bid < 2896) { src = kw;   dst = wkb;   i = (bid - 2384) * 256 + t; }
    else                 { src = cw;   dst = wcb;   i = (bid - 2896) * 256 + t; }
    const float4 a = reinterpret_cast<const float4*>(src)[i * 2 + 0];
    const float4 b = reinterpret_cast<const float4*>(src)[i * 2 + 1];
    ushort8 o;
    o[0] = f2bf(a.x); o[1] = f2bf(a.y); o[2] = f2bf(a.z); o[3] = f2bf(a.w);
    o[4] = f2bf(b.x); o[5] = f2bf(b.y); o[6] = f2bf(b.z); o[7] = f2bf(b.w);
    *reinterpret_cast<ushort8*>(&dst[i * 8]) = o;
}

// ---------------------------------------------------------------------------
// Fused mid kernel: blocks [0,1200) = bf16 MFMA GEMM NT (128x64, BK=64, dbuf);
// blocks [1200,4400) = pos_fc1. Independent work mixed per-CU so pos's VALU
// fills gemm's memory/barrier stalls (m114 MFMA/VALU pipe overlap).
// ---------------------------------------------------------------------------
__global__ __launch_bounds__(256) void mid_kernel(
    const unsigned short* __restrict__ A,
    const unsigned short* __restrict__ Wq,
    const unsigned short* __restrict__ Wk,
    const unsigned short* __restrict__ Wc,
    const float* __restrict__ bq, const float* __restrict__ bk,
    unsigned short* __restrict__ Q16, unsigned short* __restrict__ K16,
    unsigned short* __restrict__ F16,
    const float* __restrict__ prep, const float* __restrict__ fc1_w,
    const float* __restrict__ fc1_b,
    const unsigned char* __restrict__ mask8, const int* __restrict__ mask32,
    const int* __restrict__ flag, unsigned short* __restrict__ wm)
{
    __shared__ char smem[49152];

    const int bid = blockIdx.x;
    const int t = threadIdx.x;
    const int lane = t & 63;
    const int lo = lane & 15, hi = lane >> 4;

    if (bid < 1200) {
        // =================== GEMM part ===================
        short* As0 = (short*)smem;
        short* As1 = (short*)(smem + 16384);
        short* Bs0 = (short*)(smem + 32768);
        short* Bs1 = (short*)(smem + 40960);

        const int z = bid / 400;
        const int rem = bid % 400;
        const int m0 = (rem % 25) * 128;
        const int n0 = (rem / 25) * 64;

        const unsigned short* W = (z == 0) ? Wq : (z == 1) ? Wk : Wc;
        const float* bias        = (z == 0) ? bq : (z == 1) ? bk : nullptr;
        unsigned short* O        = (z == 0) ? Q16 : (z == 1) ? K16 : F16;

        const int wid = t >> 6;
        const int wr = wid >> 1, wc = wid & 1;

        f32x4 acc[4][2] = {};

        auto STAGE = [&](short* dA, short* dB, int k0) {
#pragma unroll
            for (int c = 0; c < 4; ++c) {
                const int idx16 = c * 256 + t;
                const int row = idx16 >> 3;
                const int colb = ((idx16 & 7) * 16) ^ ((row & 7) << 4);
                load_lds16((const char*)(A + (size_t)(m0 + row) * D_ + k0) + colb,
                           (char*)dA + (c * 256 + wid * 64) * 16);
            }
#pragma unroll
            for (int c = 0; c < 2; ++c) {
                const int idx16 = c * 256 + t;
                const int row = idx16 >> 3;
                const int colb = ((idx16 & 7) * 16) ^ ((row & 7) << 4);
                load_lds16((const char*)(W + (size_t)(n0 + row) * D_ + k0) + colb,
                           (char*)dB + (c * 256 + wid * 64) * 16);
            }
        };

        auto COMPUTE = [&](const short* sA, const short* sB) {
#pragma unroll
            for (int ks = 0; ks < 2; ++ks) {
                short8 afr[4], bfr[2];
                const int kb = ks * 64 + hi * 16;
#pragma unroll
                for (int f = 0; f < 4; ++f) {
                    const int am = wr * 64 + f * 16 + lo;
                    afr[f] = *reinterpret_cast<const short8*>(
                        (const char*)sA + am * 128 + (kb ^ ((am & 7) << 4)));
                }
#pragma unroll
                for (int j = 0; j < 2; ++j) {
                    const int bn = wc * 32 + j * 16 + lo;
                    bfr[j] = *reinterpret_cast<const short8*>(
                        (const char*)sB + bn * 128 + (kb ^ ((bn & 7) << 4)));
                }
#pragma unroll
                for (int i = 0; i < 4; ++i)
#pragma unroll
                    for (int j = 0; j < 2; ++j)
                        acc[i][j] = __builtin_amdgcn_mfma_f32_16x16x32_bf16(
                            afr[i], bfr[j], acc[i][j], 0, 0, 0);
            }
        };

        STAGE(As0, Bs0, 0);
        __syncthreads();
        for (int it = 0; it < 16; it += 2) {
            STAGE(As1, Bs1, (it + 1) << 6);
            COMPUTE(As0, Bs0);
            __syncthreads();
            if (it + 2 < 16) STAGE(As0, Bs0, (it + 2) << 6);
            COMPUTE(As1, Bs1);
            __syncthreads();
        }

#pragma unroll
        for (int j = 0; j < 2; ++j) {
            const int col = n0 + wc * 32 + j * 16 + lo;
            const float bv = bias ? bias[col] : 0.0f;
#pragma unroll
            for (int i = 0; i < 4; ++i) {
                const int mbase = m0 + wr * 64 + i * 16 + hi * 4;
#pragma unroll
                for (int r = 0; r < 4; ++r)
                    O[(size_t)(mbase + r) * D_ + col] = f2bf(acc[i][j][r] + bv);
            }
        }
        return;
    }

    // =================== pos_fc1 part ===================
    unsigned short* embh = (unsigned short*)smem;            // 16128 B
    unsigned short* w1h  = (unsigned short*)(smem + 16128);  // 4608 B
    float* b1   = (float*)(smem + 20736);
    float* tbl  = (float*)(smem + 20864);
    float (*pos4)[4] = (float (*)[4])(smem + 20896);

    const int pb = bid - 1200;
    const int b = pb / N_;
    const int q = pb % N_;
    const int w = t >> 6;

    const float4 pq0 = *reinterpret_cast<const float4*>(prep + (size_t)(b * N_ + q) * 8);
    const float4 pq1 = *reinterpret_cast<const float4*>(prep + (size_t)(b * N_ + q) * 8 + 4);
    const float cxq = pq0.x, cyq = pq0.y, lbwq = pq0.z, lbhq = pq0.w;
    const float rbwq = pq1.x, rbhq = pq1.y;

    for (int i = t; i < G_ * FD_; i += 256)
        w1h[(i >> 6) * 72 + (i & 63)] = f2h(fc1_w[i]);
    if (t < G_) b1[t] = fc1_b[t];
    if (t < 8)  tbl[t] = 100.0f / powf(1000.0f, (float)t * 0.125f);
    for (int i = t; i < 12 * 64; i += 256)
        embh[(100 + (i >> 6)) * 72 + (i & 63)] = 0;

    if (t < N_) {
        const float4 p0 = *reinterpret_cast<const float4*>(prep + (size_t)(b * N_ + t) * 8);
        pos4[t][0] = __logf(fmaxf(fabsf(cxq - p0.x) * rbwq, 1e-3f));
        pos4[t][1] = __logf(fmaxf(fabsf(cyq - p0.y) * rbhq, 1e-3f));
        pos4[t][2] = lbwq - p0.z;
        pos4[t][3] = lbhq - p0.w;
    }
    __syncthreads();

    for (int idx = t; idx < N_ * 32; idx += 256) {
        const int k = idx >> 5;
        const int p = (idx >> 3) & 3;
        const int j = idx & 7;
        const float dv = pos4[k][p] * tbl[j];
        embh[k * 72 + p * 16 + j]     = f2h(__sinf(dv));
        embh[k * 72 + p * 16 + 8 + j] = f2h(__cosf(dv));
    }
    __syncthreads();

    const bool bytemask = (*flag != 0);
    const int xq = q & 7;
    for (int tid = w; tid < 14; tid += 4) {
        const int mt = tid >> 1, nt = tid & 1;
        f32x4 d = {};
#pragma unroll
        for (int ks = 0; ks < 2; ++ks) {
            const short8 af = *reinterpret_cast<const short8*>(
                embh + (mt * 16 + lo) * 72 + ks * 32 + hi * 8);
            const short8 bf = *reinterpret_cast<const short8*>(
                w1h + (nt * 16 + lo) * 72 + ks * 32 + hi * 8);
            d = __builtin_amdgcn_mfma_f32_16x16x32_f16(af, bf, d, 0, 0, 0);
        }
        const int g = nt * 16 + lo;
        const int k0 = mt * 16 + hi * 4;
        const float bb = b1[g];
        unsigned int mby = 0;
        uint4 mi = {};
        if (k0 < N_) {
            const size_t midx = ((size_t)(b * N_ + q) * G_ + g) * N_ + k0;
            if (bytemask) mby = *(const unsigned int*)(mask8 + midx);
            else          mi  = *(const uint4*)(mask32 + midx);
        }
        ushort4v ov;
#pragma unroll
        for (int r = 0; r < 4; ++r) {
            const int k = k0 + r;
            const bool msk = bytemask
                ? (((mby >> (8 * r)) & 0xffu) != 0u)
                : ((r == 0 ? mi.x : r == 1 ? mi.y : r == 2 ? mi.z : mi.w) != 0u);
            const float aff = d[r] + bb;
            const float lv = __logf(fmaxf(fmaxf(aff, 0.0f), 1e-6f));
            ov[r] = f2h((k >= N_ || msk) ? -65504.0f : lv);
        }
        const size_t row = (size_t)(b * N_ + q) * G_ + g;   // [b][q][g]
        char* dst = (char*)wm + row * 256 + ((2 * k0) ^ (xq << 4));
        *reinterpret_cast<ushort4v*>(dst) = ov;
    }
}

// ---------------------------------------------------------------------------
// MFMA attention: one block per (b,g), 4 waves, one barrier.
// ---------------------------------------------------------------------------
__global__ __launch_bounds__(256) void attn_mfma(
    const unsigned short* __restrict__ qb, const unsigned short* __restrict__ kb,
    const unsigned short* __restrict__ fk16, const unsigned short* __restrict__ wm,
    const float* __restrict__ feat, const float* __restrict__ conv_b,
    float* __restrict__ out)
{
    __shared__ unsigned short PW[128 * 128];   // 32KB
    __shared__ unsigned short FL[DG_ * 128];   // 8KB

    const int bg = blockIdx.x;
    const int b = bg >> 5, g = bg & 31;
    const int t = threadIdx.x;
    const int lane = t & 63;
    const int w = t >> 6;
    const int lo = lane & 15, hi = lane >> 4;
    const float scale = 0.17677669529663687f;  // 1/sqrt(32)

    {
        const char* wbase = (const char*)wm + ((size_t)b * N_ * G_ + g) * 256;
        for (int u = t; u < 1600; u += 256) {
            const int qq = u >> 4, seg = u & 15;
            load_lds16(wbase + (size_t)qq * (G_ * 256) + seg * 16,
                       (char*)PW + u * 16);
        }
    }
    for (int u = t; u < DG_ * 28; u += 256) {
        const int dg = u / 28, n = 100 + u % 28;
        *(unsigned short*)((char*)FL + dg * 256 +
                           (((n >> 3) ^ (dg & 7)) << 4) + (n & 7) * 2) = 0;
    }
    for (int u = t; u < 400; u += 256) {
        const int n = u >> 2, c4 = u & 3;
        const ushort8 v = *reinterpret_cast<const ushort8*>(
            fk16 + (size_t)(b * N_ + n) * D_ + g * DG_ + c4 * 8);
#pragma unroll
        for (int j = 0; j < 8; ++j) {
            const int dg = c4 * 8 + j;
            *(unsigned short*)((char*)FL + dg * 256 +
                               (((n >> 3) ^ j) << 4) + (n & 7) * 2) = v[j];
        }
    }

    short8 qf[2], kf[7];
#pragma unroll
    for (int mtl = 0; mtl < 2; ++mtl) {
        const int row = w * 32 + mtl * 16 + lo;
        const int rc = row < N_ ? row : N_ - 1;
        qf[mtl] = *reinterpret_cast<const short8*>(
            qb + (size_t)(b * N_ + rc) * D_ + g * DG_ + hi * 8);
    }
#pragma unroll
    for (int ct = 0; ct < 7; ++ct) {
        const int kr = ct * 16 + lo;
        const int krc = kr < N_ ? kr : N_ - 1;
        kf[ct] = *reinterpret_cast<const short8*>(
            kb + (size_t)(b * N_ + krc) * D_ + g * DG_ + hi * 8);
    }

    __syncthreads();

    f32x4 s[2][7];
#pragma unroll
    for (int mtl = 0; mtl < 2; ++mtl)
#pragma unroll
        for (int ct = 0; ct < 7; ++ct) {
            f32x4 z = {};
            s[mtl][ct] = __builtin_amdgcn_mfma_f32_16x16x32_bf16(
                qf[mtl], kf[ct], z, 0, 0, 0);
        }

#pragma unroll
    for (int mtl = 0; mtl < 2; ++mtl) {
        const int qr0 = w * 32 + mtl * 16 + hi * 4;
#pragma unroll
        for (int ct = 0; ct < 7; ++ct) {
            const int k = ct * 16 + lo;
#pragma unroll
            for (int r = 0; r < 4; ++r) {
                const int row = qr0 + r;
                const float wv = h2f(*(const unsigned short*)(
                    (const char*)PW + row * 256 + ((2 * k) ^ ((row & 7) << 4))));
                s[mtl][ct][r] = s[mtl][ct][r] * scale + wv;
            }
        }
    }

    float sm[2][4];
#pragma unroll
    for (int mtl = 0; mtl < 2; ++mtl) {
        f32x4 mv = s[mtl][0];
#pragma unroll
        for (int ct = 1; ct < 7; ++ct)
#pragma unroll
            for (int r = 0; r < 4; ++r) mv[r] = fmaxf(mv[r], s[mtl][ct][r]);
        float mx[4];
#pragma unroll
        for (int r = 0; r < 4; ++r) {
            float m = mv[r];
            m = fmaxf(m, __shfl_xor(m, 1));
            m = fmaxf(m, __shfl_xor(m, 2));
            m = fmaxf(m, __shfl_xor(m, 4));
            m = fmaxf(m, __shfl_xor(m, 8));
            mx[r] = m;
        }
        f32x4 sv = {};
#pragma unroll
        for (int ct = 0; ct < 7; ++ct)
#pragma unroll
            for (int r = 0; r < 4; ++r) {
                const float e = __expf(s[mtl][ct][r] - mx[r]);
                s[mtl][ct][r] = e;
                sv[r] += e;
            }
#pragma unroll
        for (int r = 0; r < 4; ++r) {
            float ss = sv[r];
            ss += __shfl_xor(ss, 1);
            ss += __shfl_xor(ss, 2);
            ss += __shfl_xor(ss, 4);
            ss += __shfl_xor(ss, 8);
            sm[mtl][r] = 1.0f / ss;
        }
    }

#pragma unroll
    for (int mtl = 0; mtl < 2; ++mtl) {
        const int qr0 = w * 32 + mtl * 16 + hi * 4;
#pragma unroll
        for (int ct = 0; ct < 7; ++ct) {
            const int col = ct * 16 + lo;
#pragma unroll
            for (int r = 0; r < 4; ++r) {
                const int row = qr0 + r;
                *(unsigned short*)((char*)PW + row * 256 +
                                   ((2 * col) ^ ((row & 7) << 4))) =
                    f2bf(s[mtl][ct][r] * sm[mtl][r]);
            }
        }
    }
    {
        const int zr = w * 32 + (lane & 31);
        const int zg = 14 + (lane >> 5);
        short8 zs = {};
        *reinterpret_cast<short8*>(
            (char*)PW + zr * 256 + ((zg * 16) ^ ((zr & 7) << 4))) = zs;
    }

    f32x4 o[2][2] = {};
#pragma unroll
    for (int ks = 0; ks < 4; ++ks) {
        short8 pa[2], fb[2];
#pragma unroll
        for (int mtl = 0; mtl < 2; ++mtl) {
            const int prow = w * 32 + mtl * 16 + lo;
            pa[mtl] = *reinterpret_cast<const short8*>(
                (const char*)PW + prow * 256 +
                ((ks * 64 + hi * 16) ^ ((prow & 7) << 4)));
        }
#pragma unroll
        for (int nt = 0; nt < 2; ++nt) {
            const int dg = nt * 16 + lo;
            fb[nt] = *reinterpret_cast<const short8*>(
                (const char*)FL + dg * 256 +
                ((ks * 64 + hi * 16) ^ ((dg & 7) << 4)));
        }
#pragma unroll
        for (int mtl = 0; mtl < 2; ++mtl)
#pragma unroll
            for (int nt = 0; nt < 2; ++nt)
                o[mtl][nt] = __builtin_amdgcn_mfma_f32_16x16x32_bf16(
                    pa[mtl], fb[nt], o[mtl][nt], 0, 0, 0);
    }

#pragma unroll
    for (int mtl = 0; mtl < 2; ++mtl) {
        const int qr0 = w * 32 + mtl * 16 + hi * 4;
#pragma unroll
        for (int nt = 0; nt < 2; ++nt) {
            const int col = g * DG_ + nt * 16 + lo;
            const float cb = conv_b[col];
#pragma unroll
            for (int r = 0; r < 4; ++r) {
                const int q = qr0 + r;
                if (q < N_) {
                    const size_t gi = (size_t)(b * N_ + q) * D_ + col;
                    out[gi] = fmaxf(feat[gi] + o[mtl][nt][r] + cb, 0.0f);
                }
            }
        }
    }
}

// ---------------------------------------------------------------------------
extern "C" void kernel_launch(void* const* d_in, const int* in_sizes, int n_in,
                              void* d_out, int out_size, void* d_ws, size_t ws_size,
                              hipStream_t stream)
{
    const float* feat   = (const float*)d_in[0];
    const float* bbox   = (const float*)d_in[1];
    const void*  maskp  = d_in[2];
    const float* fc1_w  = (const float*)d_in[3];
    const float* fc1_b  = (const float*)d_in[4];
    const float* q_w    = (const float*)d_in[5];
    const float* q_b    = (const float*)d_in[6];
    const float* k_w    = (const float*)d_in[7];
    const float* k_b    = (const float*)d_in[8];
    const float* conv_w = (const float*)d_in[9];
    const float* conv_b = (const float*)d_in[10];

    const int BN_D  = B_ * N_ * D_;          // 3,276,800
    const int DD    = D_ * D_;               // 1,048,576
    const int WM_N  = B_ * G_ * N_ * 128;    // 13,107,200

    unsigned short* ws16 = (unsigned short*)d_ws;
    unsigned short* qb16  = ws16;                 // BN_D
    unsigned short* kb16  = qb16 + BN_D;          // BN_D
    unsigned short* fk16  = kb16 + BN_D;          // BN_D
    unsigned short* wm    = fk16 + BN_D;          // WM_N
    int* flag = (int*)(wm + WM_N);                // 64 ints
    float* prep = (float*)(flag + 64);            // 3200*8 floats
    // cast buffers live concurrently with wm (gemm reads them while pos
    // writes wm in the same fused dispatch) -> dedicated space after prep.
    unsigned short* featb = (unsigned short*)(prep + B_ * N_ * 8);
    unsigned short* wqb   = featb + BN_D;
    unsigned short* wkb   = wqb + DD;
    unsigned short* wcb   = wkb + DD;

    hipMemsetAsync(flag, 0, sizeof(int), stream);
    prep_kernel<<<3408, 256, 0, stream>>>((const unsigned int*)maskp, flag,
                                          bbox, prep, feat, featb,
                                          q_w, wqb, k_w, wkb, conv_w, wcb);

    mid_kernel<<<4400, 256, 0, stream>>>(featb, wqb, wkb, wcb, q_b, k_b,
                                         qb16, kb16, fk16,
                                         prep, fc1_w, fc1_b,
                                         (const unsigned char*)maskp,
                                         (const int*)maskp, flag, wm);

    attn_mfma<<<B_ * G_, 256, 0, stream>>>(qb16, kb16, fk16, wm,
                                           feat, conv_b, (float*)d_out);
}

// Round 10
// 96.581 us; speedup vs baseline: 1.0064x; 1.0064x over previous
//
#include <hip/hip_runtime.h>
#include <math.h>

#define B_  32
#define N_  100
#define G_  32
#define D_  1024
#define DG_ 32
#define FD_ 64

typedef __attribute__((ext_vector_type(8))) short short8;
typedef __attribute__((ext_vector_type(8))) unsigned short ushort8;
typedef __attribute__((ext_vector_type(4))) unsigned short ushort4v;
typedef __attribute__((ext_vector_type(4))) float f32x4;

__device__ inline unsigned short f2bf(float f) {
    unsigned int x = __float_as_uint(f);
    unsigned int r = (x + 0x7fffu + ((x >> 16) & 1u)) >> 16;  // RNE
    return (unsigned short)r;
}
__device__ inline unsigned short f2h(float f) {
    _Float16 h = (_Float16)f;
    return __builtin_bit_cast(unsigned short, h);
}
__device__ inline float h2f(unsigned short u) {
    return (float)__builtin_bit_cast(_Float16, u);
}
__device__ inline void load_lds16(const void* g, void* l) {
    __builtin_amdgcn_global_load_lds(
        (const __attribute__((address_space(1))) void*)g,
        (__attribute__((address_space(3))) void*)l, 16, 0, 0);
}

// ---------------------------------------------------------------------------
// Fused prep: [0,256) mask detect (1/8 scan) | [256,272) bbox prep |
// [272,1872) feat cast | [1872,2384) q_w | [2384,2896) k_w | [2896,3408) conv_w.
// ---------------------------------------------------------------------------
__global__ __launch_bounds__(256) void prep_kernel(
    const unsigned int* __restrict__ mask, int* __restrict__ flag,
    const float* __restrict__ bbox, float* __restrict__ prep,
    const float* __restrict__ feat, unsigned short* __restrict__ featb,
    const float* __restrict__ qw, unsigned short* __restrict__ wqb,
    const float* __restrict__ kw, unsigned short* __restrict__ wkb,
    const float* __restrict__ cw, unsigned short* __restrict__ wcb)
{
    const int bid = blockIdx.x;
    const int t = threadIdx.x;
    if (bid < 256) {
        const int nwords = (B_ * N_ * G_ * N_) / 4 / 8;   // 1/8 scan
        int v = 0;
        for (int i = bid * 256 + t; i < nwords; i += 256 * 256)
            v |= (mask[i] > 1u) ? 1 : 0;
        if (__any(v) && (t & 63) == 0) atomicOr(flag, 1);
        return;
    }
    if (bid < 272) {
        const int i = (bid - 256) * 256 + t;
        if (i < B_ * N_) {
            const float4 bb = *reinterpret_cast<const float4*>(bbox + (size_t)i * 4);
            const float bw = bb.z - bb.x + 1.0f, bh = bb.w - bb.y + 1.0f;
            float4 o0, o1;
            o0.x = 0.5f * (bb.x + bb.z);
            o0.y = 0.5f * (bb.y + bb.w);
            o0.z = __logf(bw);
            o0.w = __logf(bh);
            o1.x = 1.0f / bw;
            o1.y = 1.0f / bh;
            o1.z = 0.0f; o1.w = 0.0f;
            *reinterpret_cast<float4*>(prep + (size_t)i * 8)     = o0;
            *reinterpret_cast<float4*>(prep + (size_t)i * 8 + 4) = o1;
        }
        return;
    }
    const float* src;
    unsigned short* dst;
    int i;
    if (bid < 1872)      { src = feat; dst = featb; i = (bid - 272) * 256 + t; }
    else if (bid < 2384) { src = qw;   dst = wqb;   i = (bid - 1872) * 256 + t; }
    else if (bid < 2896) { src = kw;   dst = wkb;   i = (bid - 2384) * 256 + t; }
    else                 { src = cw;   dst = wcb;   i = (bid - 2896) * 256 + t; }
    const float4 a = reinterpret_cast<const float4*>(src)[i * 2 + 0];
    const float4 b = reinterpret_cast<const float4*>(src)[i * 2 + 1];
    ushort8 o;
    o[0] = f2bf(a.x); o[1] = f2bf(a.y); o[2] = f2bf(a.z); o[3] = f2bf(a.w);
    o[4] = f2bf(b.x); o[5] = f2bf(b.y); o[6] = f2bf(b.z); o[7] = f2bf(b.w);
    *reinterpret_cast<ushort8*>(&dst[i * 8]) = o;
}

// ---------------------------------------------------------------------------
// bf16 MFMA GEMM NT, 128x64 tile, BK=64, double-buffered LDS (T3 2-phase).
// z=0: q(+q_b). z=1: k(+k_b). z=2: fk (no bias). All outputs bf16.
// ---------------------------------------------------------------------------
__global__ __launch_bounds__(256) void mfma_gemm_nt(
    const unsigned short* __restrict__ A,
    const unsigned short* __restrict__ Wq,
    const unsigned short* __restrict__ Wk,
    const unsigned short* __restrict__ Wc,
    const float* __restrict__ bq, const float* __restrict__ bk,
    unsigned short* __restrict__ Q16, unsigned short* __restrict__ K16,
    unsigned short* __restrict__ F16)
{
    __shared__ short As0[128 * 64], As1[128 * 64];   // 16 KB each
    __shared__ short Bs0[64 * 64],  Bs1[64 * 64];    // 8 KB each

    const int z = blockIdx.z;
    const unsigned short* W = (z == 0) ? Wq : (z == 1) ? Wk : Wc;
    const float* bias        = (z == 0) ? bq : (z == 1) ? bk : nullptr;
    unsigned short* O        = (z == 0) ? Q16 : (z == 1) ? K16 : F16;

    const int m0 = blockIdx.x * 128;
    const int n0 = blockIdx.y * 64;
    const int t = threadIdx.x;
    const int lane = t & 63;
    const int wid = t >> 6;
    const int wr = wid >> 1, wc = wid & 1;
    const int lo = lane & 15, hi = lane >> 4;

    f32x4 acc[4][2] = {};

    auto STAGE = [&](short* dA, short* dB, int k0) {
#pragma unroll
        for (int c = 0; c < 4; ++c) {
            const int idx16 = c * 256 + t;
            const int row = idx16 >> 3;
            const int colb = ((idx16 & 7) * 16) ^ ((row & 7) << 4);
            load_lds16((const char*)(A + (size_t)(m0 + row) * D_ + k0) + colb,
                       (char*)dA + (c * 256 + wid * 64) * 16);
        }
#pragma unroll
        for (int c = 0; c < 2; ++c) {
            const int idx16 = c * 256 + t;
            const int row = idx16 >> 3;
            const int colb = ((idx16 & 7) * 16) ^ ((row & 7) << 4);
            load_lds16((const char*)(W + (size_t)(n0 + row) * D_ + k0) + colb,
                       (char*)dB + (c * 256 + wid * 64) * 16);
        }
    };

    auto COMPUTE = [&](const short* sA, const short* sB) {
#pragma unroll
        for (int ks = 0; ks < 2; ++ks) {
            short8 afr[4], bfr[2];
            const int kb = ks * 64 + hi * 16;
#pragma unroll
            for (int f = 0; f < 4; ++f) {
                const int am = wr * 64 + f * 16 + lo;
                afr[f] = *reinterpret_cast<const short8*>(
                    (const char*)sA + am * 128 + (kb ^ ((am & 7) << 4)));
            }
#pragma unroll
            for (int j = 0; j < 2; ++j) {
                const int bn = wc * 32 + j * 16 + lo;
                bfr[j] = *reinterpret_cast<const short8*>(
                    (const char*)sB + bn * 128 + (kb ^ ((bn & 7) << 4)));
            }
#pragma unroll
            for (int i = 0; i < 4; ++i)
#pragma unroll
                for (int j = 0; j < 2; ++j)
                    acc[i][j] = __builtin_amdgcn_mfma_f32_16x16x32_bf16(
                        afr[i], bfr[j], acc[i][j], 0, 0, 0);
        }
    };

    STAGE(As0, Bs0, 0);
    __syncthreads();
    for (int it = 0; it < 16; it += 2) {
        STAGE(As1, Bs1, (it + 1) << 6);
        COMPUTE(As0, Bs0);
        __syncthreads();
        if (it + 2 < 16) STAGE(As0, Bs0, (it + 2) << 6);
        COMPUTE(As1, Bs1);
        __syncthreads();
    }

#pragma unroll
    for (int j = 0; j < 2; ++j) {
        const int col = n0 + wc * 32 + j * 16 + lo;
        const float bv = bias ? bias[col] : 0.0f;
#pragma unroll
        for (int i = 0; i < 4; ++i) {
            const int mbase = m0 + wr * 64 + i * 16 + hi * 4;
#pragma unroll
            for (int r = 0; r < 4; ++r)
                O[(size_t)(mbase + r) * D_ + col] = f2bf(acc[i][j][r] + bv);
        }
    }
}

// ---------------------------------------------------------------------------
// pos_fc1: pairwise pos (hoisted, division-free) + f16 emb + fc1 MFMA.
// W-FORM OUTPUT: wm[b][q][g][128] f16 = max(aff, 1e-6), masked/pad = 0.
// (softmax shift-invariance: softmax(aff_qk + log w) == w*e^aff / sum.)
// No log here, no -inf handling in attn. Granule-swizzled ^(q&7).
// ---------------------------------------------------------------------------
__global__ __launch_bounds__(256) void pos_fc1_kernel(
    const float* __restrict__ prep, const float* __restrict__ fc1_w,
    const float* __restrict__ fc1_b,
    const unsigned char* __restrict__ mask8, const int* __restrict__ mask32,
    const int* __restrict__ flag, unsigned short* __restrict__ wm)
{
    __shared__ unsigned short embh[112 * 72];
    __shared__ unsigned short w1h[G_ * 72];
    __shared__ float b1[G_];
    __shared__ float tbl[8];
    __shared__ float pos4[N_][4];

    const int b = blockIdx.x / N_;
    const int q = blockIdx.x % N_;
    const int t = threadIdx.x;
    const int lane = t & 63;
    const int w = t >> 6;
    const int lo = lane & 15, hi = lane >> 4;

    const float4 pq0 = *reinterpret_cast<const float4*>(prep + (size_t)(b * N_ + q) * 8);
    const float4 pq1 = *reinterpret_cast<const float4*>(prep + (size_t)(b * N_ + q) * 8 + 4);
    const float cxq = pq0.x, cyq = pq0.y, lbwq = pq0.z, lbhq = pq0.w;
    const float rbwq = pq1.x, rbhq = pq1.y;

    for (int i = t; i < G_ * FD_; i += 256)
        w1h[(i >> 6) * 72 + (i & 63)] = f2h(fc1_w[i]);
    if (t < G_) b1[t] = fc1_b[t];
    if (t < 8)  tbl[t] = 100.0f / powf(1000.0f, (float)t * 0.125f);
    for (int i = t; i < 12 * 64; i += 256)
        embh[(100 + (i >> 6)) * 72 + (i & 63)] = 0;

    if (t < N_) {
        const float4 p0 = *reinterpret_cast<const float4*>(prep + (size_t)(b * N_ + t) * 8);
        pos4[t][0] = __logf(fmaxf(fabsf(cxq - p0.x) * rbwq, 1e-3f));
        pos4[t][1] = __logf(fmaxf(fabsf(cyq - p0.y) * rbhq, 1e-3f));
        pos4[t][2] = lbwq - p0.z;
        pos4[t][3] = lbhq - p0.w;
    }
    __syncthreads();

    for (int idx = t; idx < N_ * 32; idx += 256) {
        const int k = idx >> 5;
        const int p = (idx >> 3) & 3;
        const int j = idx & 7;
        const float dv = pos4[k][p] * tbl[j];
        embh[k * 72 + p * 16 + j]     = f2h(__sinf(dv));
        embh[k * 72 + p * 16 + 8 + j] = f2h(__cosf(dv));
    }
    __syncthreads();

    const bool bytemask = (*flag != 0);
    const int xq = q & 7;
    for (int tid = w; tid < 14; tid += 4) {
        const int mt = tid >> 1, nt = tid & 1;
        f32x4 d = {};
#pragma unroll
        for (int ks = 0; ks < 2; ++ks) {
            const short8 af = *reinterpret_cast<const short8*>(
                embh + (mt * 16 + lo) * 72 + ks * 32 + hi * 8);
            const short8 bf = *reinterpret_cast<const short8*>(
                w1h + (nt * 16 + lo) * 72 + ks * 32 + hi * 8);
            d = __builtin_amdgcn_mfma_f32_16x16x32_f16(af, bf, d, 0, 0, 0);
        }
        const int g = nt * 16 + lo;
        const int k0 = mt * 16 + hi * 4;
        const float bb = b1[g];
        unsigned int mby = 0;
        uint4 mi = {};
        if (k0 < N_) {
            const size_t midx = ((size_t)(b * N_ + q) * G_ + g) * N_ + k0;
            if (bytemask) mby = *(const unsigned int*)(mask8 + midx);
            else          mi  = *(const uint4*)(mask32 + midx);
        }
        ushort4v ov;
#pragma unroll
        for (int r = 0; r < 4; ++r) {
            const int k = k0 + r;
            const bool msk = bytemask
                ? (((mby >> (8 * r)) & 0xffu) != 0u)
                : ((r == 0 ? mi.x : r == 1 ? mi.y : r == 2 ? mi.z : mi.w) != 0u);
            // w-form: weight, not log(weight). masked/pad -> exact 0.
            ov[r] = (k >= N_ || msk) ? (unsigned short)0
                                     : f2h(fmaxf(d[r] + bb, 1e-6f));
        }
        const size_t row = (size_t)(b * N_ + q) * G_ + g;   // [b][q][g]
        char* dst = (char*)wm + row * 256 + ((2 * k0) ^ (xq << 4));
        *reinterpret_cast<ushort4v*>(dst) = ov;
    }
}

// ---------------------------------------------------------------------------
// MFMA attention: one block per (b,g), 4 waves, one barrier.
// W-form softmax: p = exp((s - mx)*scale) * w[k]; w==0 kills masked/pad.
// ---------------------------------------------------------------------------
__global__ __launch_bounds__(256) void attn_mfma(
    const unsigned short* __restrict__ qb, const unsigned short* __restrict__ kb,
    const unsigned short* __restrict__ fk16, const unsigned short* __restrict__ wm,
    const float* __restrict__ feat, const float* __restrict__ conv_b,
    float* __restrict__ out)
{
    __shared__ unsigned short PW[128 * 128];   // 32KB
    __shared__ unsigned short FL[DG_ * 128];   // 8KB

    const int bg = blockIdx.x;
    const int b = bg >> 5, g = bg & 31;
    const int t = threadIdx.x;
    const int lane = t & 63;
    const int w = t >> 6;
    const int lo = lane & 15, hi = lane >> 4;
    const float scale = 0.17677669529663687f;  // 1/sqrt(32)

    // ---- stage wm rows (q-strided granules) ----
    {
        const char* wbase = (const char*)wm + ((size_t)b * N_ * G_ + g) * 256;
        for (int u = t; u < 1600; u += 256) {
            const int qq = u >> 4, seg = u & 15;
            load_lds16(wbase + (size_t)qq * (G_ * 256) + seg * 16,
                       (char*)PW + u * 16);
        }
    }
    // ---- FL pad zero + transpose from fk16 ----
    for (int u = t; u < DG_ * 28; u += 256) {
        const int dg = u / 28, n = 100 + u % 28;
        *(unsigned short*)((char*)FL + dg * 256 +
                           (((n >> 3) ^ (dg & 7)) << 4) + (n & 7) * 2) = 0;
    }
    for (int u = t; u < 400; u += 256) {
        const int n = u >> 2, c4 = u & 3;
        const ushort8 v = *reinterpret_cast<const ushort8*>(
            fk16 + (size_t)(b * N_ + n) * D_ + g * DG_ + c4 * 8);
#pragma unroll
        for (int j = 0; j < 8; ++j) {
            const int dg = c4 * 8 + j;
            *(unsigned short*)((char*)FL + dg * 256 +
                               (((n >> 3) ^ j) << 4) + (n & 7) * 2) = v[j];
        }
    }

    // ---- Q/K fragments direct from global bf16 ----
    short8 qf[2], kf[7];
#pragma unroll
    for (int mtl = 0; mtl < 2; ++mtl) {
        const int row = w * 32 + mtl * 16 + lo;
        const int rc = row < N_ ? row : N_ - 1;
        qf[mtl] = *reinterpret_cast<const short8*>(
            qb + (size_t)(b * N_ + rc) * D_ + g * DG_ + hi * 8);
    }
#pragma unroll
    for (int ct = 0; ct < 7; ++ct) {
        const int kr = ct * 16 + lo;
        const int krc = kr < N_ ? kr : N_ - 1;
        kf[ct] = *reinterpret_cast<const short8*>(
            kb + (size_t)(b * N_ + krc) * D_ + g * DG_ + hi * 8);
    }

    __syncthreads();   // staging complete

    // ---- QK^T ----
    f32x4 s[2][7];
#pragma unroll
    for (int mtl = 0; mtl < 2; ++mtl)
#pragma unroll
        for (int ct = 0; ct < 7; ++ct) {
            f32x4 z = {};
            s[mtl][ct] = __builtin_amdgcn_mfma_f32_16x16x32_bf16(
                qf[mtl], kf[ct], z, 0, 0, 0);
        }

    // ---- softmax: mx over raw s; p = exp((s-mx)*scale) * w ----
    float sm[2][4];
#pragma unroll
    for (int mtl = 0; mtl < 2; ++mtl) {
        const int qr0 = w * 32 + mtl * 16 + hi * 4;
        f32x4 mv = s[mtl][0];
#pragma unroll
        for (int ct = 1; ct < 7; ++ct)
#pragma unroll
            for (int r = 0; r < 4; ++r) mv[r] = fmaxf(mv[r], s[mtl][ct][r]);
        float mx[4];
#pragma unroll
        for (int r = 0; r < 4; ++r) {
            float m = mv[r];
            m = fmaxf(m, __shfl_xor(m, 1));
            m = fmaxf(m, __shfl_xor(m, 2));
            m = fmaxf(m, __shfl_xor(m, 4));
            m = fmaxf(m, __shfl_xor(m, 8));
            mx[r] = m;
        }
        f32x4 sv = {};
#pragma unroll
        for (int ct = 0; ct < 7; ++ct) {
            const int k = ct * 16 + lo;
#pragma unroll
            for (int r = 0; r < 4; ++r) {
                const int row = qr0 + r;
                const float wv = h2f(*(const unsigned short*)(
                    (const char*)PW + row * 256 + ((2 * k) ^ ((row & 7) << 4))));
                const float e = __expf((s[mtl][ct][r] - mx[r]) * scale) * wv;
                s[mtl][ct][r] = e;
                sv[r] += e;
            }
        }
#pragma unroll
        for (int r = 0; r < 4; ++r) {
            float ss = sv[r];
            ss += __shfl_xor(ss, 1);
            ss += __shfl_xor(ss, 2);
            ss += __shfl_xor(ss, 4);
            ss += __shfl_xor(ss, 8);
            sm[mtl][r] = 1.0f / ss;
        }
    }

    // ---- P -> bf16 -> PW in-place (wave-private rows) ----
#pragma unroll
    for (int mtl = 0; mtl < 2; ++mtl) {
        const int qr0 = w * 32 + mtl * 16 + hi * 4;
#pragma unroll
        for (int ct = 0; ct < 7; ++ct) {
            const int col = ct * 16 + lo;
#pragma unroll
            for (int r = 0; r < 4; ++r) {
                const int row = qr0 + r;
                *(unsigned short*)((char*)PW + row * 256 +
                                   ((2 * col) ^ ((row & 7) << 4))) =
                    f2bf(s[mtl][ct][r] * sm[mtl][r]);
            }
        }
    }
    {
        const int zr = w * 32 + (lane & 31);
        const int zg = 14 + (lane >> 5);
        short8 zs = {};
        *reinterpret_cast<short8*>(
            (char*)PW + zr * 256 + ((zg * 16) ^ ((zr & 7) << 4))) = zs;
    }

    // ---- PV ----
    f32x4 o[2][2] = {};
#pragma unroll
    for (int ks = 0; ks < 4; ++ks) {
        short8 pa[2], fb[2];
#pragma unroll
        for (int mtl = 0; mtl < 2; ++mtl) {
            const int prow = w * 32 + mtl * 16 + lo;
            pa[mtl] = *reinterpret_cast<const short8*>(
                (const char*)PW + prow * 256 +
                ((ks * 64 + hi * 16) ^ ((prow & 7) << 4)));
        }
#pragma unroll
        for (int nt = 0; nt < 2; ++nt) {
            const int dg = nt * 16 + lo;
            fb[nt] = *reinterpret_cast<const short8*>(
                (const char*)FL + dg * 256 +
                ((ks * 64 + hi * 16) ^ ((dg & 7) << 4)));
        }
#pragma unroll
        for (int mtl = 0; mtl < 2; ++mtl)
#pragma unroll
            for (int nt = 0; nt < 2; ++nt)
                o[mtl][nt] = __builtin_amdgcn_mfma_f32_16x16x32_bf16(
                    pa[mtl], fb[nt], o[mtl][nt], 0, 0, 0);
    }

    // ---- epilogue ----
#pragma unroll
    for (int mtl = 0; mtl < 2; ++mtl) {
        const int qr0 = w * 32 + mtl * 16 + hi * 4;
#pragma unroll
        for (int nt = 0; nt < 2; ++nt) {
            const int col = g * DG_ + nt * 16 + lo;
            const float cb = conv_b[col];
#pragma unroll
            for (int r = 0; r < 4; ++r) {
                const int q = qr0 + r;
                if (q < N_) {
                    const size_t gi = (size_t)(b * N_ + q) * D_ + col;
                    out[gi] = fmaxf(feat[gi] + o[mtl][nt][r] + cb, 0.0f);
                }
            }
        }
    }
}

// ---------------------------------------------------------------------------
extern "C" void kernel_launch(void* const* d_in, const int* in_sizes, int n_in,
                              void* d_out, int out_size, void* d_ws, size_t ws_size,
                              hipStream_t stream)
{
    const float* feat   = (const float*)d_in[0];
    const float* bbox   = (const float*)d_in[1];
    const void*  maskp  = d_in[2];
    const float* fc1_w  = (const float*)d_in[3];
    const float* fc1_b  = (const float*)d_in[4];
    const float* q_w    = (const float*)d_in[5];
    const float* q_b    = (const float*)d_in[6];
    const float* k_w    = (const float*)d_in[7];
    const float* k_b    = (const float*)d_in[8];
    const float* conv_w = (const float*)d_in[9];
    const float* conv_b = (const float*)d_in[10];

    const int BN_D  = B_ * N_ * D_;          // 3,276,800
    const int DD    = D_ * D_;               // 1,048,576
    const int WM_N  = B_ * G_ * N_ * 128;    // 13,107,200

    unsigned short* ws16 = (unsigned short*)d_ws;
    unsigned short* qb16  = ws16;                 // BN_D
    unsigned short* kb16  = qb16 + BN_D;          // BN_D
    unsigned short* fk16  = kb16 + BN_D;          // BN_D
    unsigned short* wm    = fk16 + BN_D;          // WM_N
    int* flag = (int*)(wm + WM_N);                // 64 ints
    float* prep = (float*)(flag + 64);            // 3200*8 floats

    // bf16 cast staging aliases wm: gemm (reader) completes before pos_fc1
    // (wm writer) starts -- stream-ordered, safe when kernels are separate.
    unsigned short* featb = wm;
    unsigned short* wqb   = featb + BN_D;
    unsigned short* wkb   = wqb + DD;
    unsigned short* wcb   = wkb + DD;

    hipMemsetAsync(flag, 0, sizeof(int), stream);
    prep_kernel<<<3408, 256, 0, stream>>>((const unsigned int*)maskp, flag,
                                          bbox, prep, feat, featb,
                                          q_w, wqb, k_w, wkb, conv_w, wcb);

    dim3 gg(B_ * N_ / 128, D_ / 64, 3);  // (25, 16, 3)
    mfma_gemm_nt<<<gg, 256, 0, stream>>>(featb, wqb, wkb, wcb, q_b, k_b,
                                         qb16, kb16, fk16);

    pos_fc1_kernel<<<B_ * N_, 256, 0, stream>>>(prep, fc1_w, fc1_b,
                                                (const unsigned char*)maskp,
                                                (const int*)maskp, flag, wm);

    attn_mfma<<<B_ * G_, 256, 0, stream>>>(qb16, kb16, fk16, wm,
                                           feat, conv_b, (float*)d_out);
}